// Round 3
// baseline (383.526 us; speedup 1.0000x reference)
//
#include <hip/hip_runtime.h>
#include <math.h>

// Problem constants
#define BATCH   2
#define LSEQ    1024
#define DMODEL  1024
#define DSTATE  16
#define DCONV   4
#define DINNER  2048
#define NROWS   (BATCH * LSEQ)   // 2048

#define LCHUNK  32
#define NCHUNK  32

typedef short  bf16x8 __attribute__((ext_vector_type(8)));
typedef float  f32x4  __attribute__((ext_vector_type(4)));

__device__ __forceinline__ unsigned short f2bf(float f) {
  unsigned int u = __builtin_bit_cast(unsigned int, f);
  u = (u + 0x7fffu + ((u >> 16) & 1u)) >> 16;   // RNE
  return (unsigned short)u;
}
__device__ __forceinline__ float bf2f(unsigned short h) {
  return __builtin_bit_cast(float, (unsigned int)h << 16);
}

__device__ __forceinline__ float softplus_f(float v) {
  return (v > 20.f) ? v : __logf(1.f + __expf(v));
}

// ---------------------------------------------------------------------------
// Fused input conversion (R13-proven). 4 regions; no zeroing needed (R3: no
// atomics anywhere).
// ---------------------------------------------------------------------------
__device__ __forceinline__ void cvt_ew_body(const float* __restrict__ s,
                                            unsigned short* __restrict__ d,
                                            int blk, int tid) {
  int i = blk * 256 + tid;
  float4 v = ((const float4*)s)[i];
  ushort4 o;
  o.x = f2bf(v.x); o.y = f2bf(v.y); o.z = f2bf(v.z); o.w = f2bf(v.w);
  ((ushort4*)d)[i] = o;
}

__device__ __forceinline__ void cvt_tr_body(const float* __restrict__ s,
                                            unsigned short* __restrict__ d,
                                            int R, int C, int c0, int r0,
                                            int tid, float (*T)[33]) {
#pragma unroll
  for (int i = 0; i < 4; ++i) {
    int e = tid + i * 256;
    int r = e >> 5, c = e & 31;
    T[r][c] = s[(size_t)(r0 + r) * C + c0 + c];
  }
  __syncthreads();
#pragma unroll
  for (int i = 0; i < 4; ++i) {
    int e = tid + i * 256;
    int c = e >> 5, r = e & 31;
    d[(size_t)(c0 + c) * R + r0 + r] = f2bf(T[r][c]);
  }
}

__global__ __launch_bounds__(256) void cvt_all(
    const float* __restrict__ x, const float* __restrict__ w_in,
    const float* __restrict__ dt_w, const float* __restrict__ out_w,
    unsigned short* __restrict__ XB, unsigned short* __restrict__ WINB,
    unsigned short* __restrict__ DTWB, unsigned short* __restrict__ OWB) {
  __shared__ float T[32][33];
  const int bid = blockIdx.x;
  const int tid = threadIdx.x;
  if (bid < 2048) {
    cvt_ew_body(x, XB, bid, tid);
  } else if (bid < 6144) {
    int t = bid - 2048;
    cvt_tr_body(w_in, WINB, 1024, 4096, (t & 127) * 32, (t >> 7) * 32, tid, T);
  } else if (bid < 10240) {
    cvt_ew_body(dt_w, DTWB, bid - 6144, tid);
  } else {
    int t = bid - 10240;
    cvt_tr_body(out_w, OWB, 2048, 1024, (t & 31) * 32, (t >> 5) * 32, tid, T);
  }
}

// ---------------------------------------------------------------------------
// bf16 MFMA GEMM (NT). R3: tile BM=256 x BN=128, BK=64, 512 threads, 8 waves
// as 2(row)x4(col), per-wave output 128x32 (acc[8][2]).
// DOUBLE-BUFFERED PREFETCH K-LOOP (T3 minimum-2-phase): stage(buf0); sync;
// loop { stage(next into buf^1); compute(buf); sync; flip }. The end-of-step
// __syncthreads (vmcnt(0)+barrier) waits on loads that have been in flight
// DURING the compute phase — vs R0-R2's stage->sync->compute which exposed
// full memory latency every K-step (counters: MfmaUtil 9%, VALU 5%, HBM 12%
// -> pure latency stall). LDS 96 KB (2x48), 1 block/CU.
// R2 lesson: NO per-element fp32 atomics — 8.4M atomicAdds cost ~60 µs
// (~7 µs/M). All epilogues are plain stores; no split-K.
// Epilogue modes: 1 = bf16 col<N1 -> C1 else C2  [in_proj u|res]
//                 2 = softplus(v+bias[col]) bf16 [dt_proj]
//                 3 = fp32 plain store           [out_proj]
// NOTE (R8/R11): NO inter-block coordination inside kernels.
// ---------------------------------------------------------------------------
__global__ __launch_bounds__(512) void mfma_gemm_nt(
    const unsigned short* __restrict__ A, int lda,
    const unsigned short* __restrict__ Bt, int ldb,
    void* __restrict__ C1v, int ld1,
    void* __restrict__ C2v, int ld2, int N1,
    const float* __restrict__ bias,
    int KS, int mode) {
  __shared__ unsigned short As[2][8 * 256 * 8];  // 2 x 32 KB [kc][row][8]
  __shared__ unsigned short Bs[2][8 * 128 * 8];  // 2 x 16 KB [kc][col][8]
  const int tid  = threadIdx.x;
  const int wave = tid >> 6;        // 0..7
  const int lane = tid & 63;
  // bijective XCD swizzle (total % 8 == 0 for all our grids)
  const int total = gridDim.x * gridDim.y;
  const int lin = blockIdx.y * gridDim.x + blockIdx.x;
  const int wg = (lin & 7) * (total >> 3) + (lin >> 3);
  const int row0 = (wg / gridDim.x) * 256;   // gridDim.x = N-tiles
  const int col0 = (wg % gridDim.x) * 128;
  const int wm0 = (wave >> 2) * 128;
  const int wn0 = (wave & 3) * 32;

  f32x4 acc[8][2];
#pragma unroll
  for (int i = 0; i < 8; ++i)
#pragma unroll
    for (int j = 0; j < 2; ++j) acc[i][j] = (f32x4){0.f, 0.f, 0.f, 0.f};

  const int lkc = lane >> 4, li = lane & 15;
  const int nsteps = KS >> 6;

  auto stage = [&](int buf, int k0) {
#pragma unroll
    for (int it = 0; it < 4; ++it) {
      int s = it * 512 + tid;        // 0..2047 A slots (16B each)
      int kc = s >> 8, r = s & 255;
      __builtin_amdgcn_global_load_lds(
          (const __attribute__((address_space(1))) void*)(A + (size_t)(row0 + r) * lda + k0 + kc * 8),
          (__attribute__((address_space(3))) void*)(&As[buf][s * 8]), 16, 0, 0);
    }
#pragma unroll
    for (int it = 0; it < 2; ++it) {
      int s = it * 512 + tid;        // 0..1023 B slots
      int kc = s >> 7, r = s & 127;
      __builtin_amdgcn_global_load_lds(
          (const __attribute__((address_space(1))) void*)(Bt + (size_t)(col0 + r) * ldb + k0 + kc * 8),
          (__attribute__((address_space(3))) void*)(&Bs[buf][s * 8]), 16, 0, 0);
    }
  };

  stage(0, 0);
  __syncthreads();                 // drain prologue stage
  int cur = 0;
  for (int t = 0; t < nsteps; ++t) {
    if (t + 1 < nsteps) stage(cur ^ 1, (t + 1) << 6);  // prefetch next tile
#pragma unroll
    for (int half = 0; half < 2; ++half) {
      bf16x8 af[8], bfr[2];
#pragma unroll
      for (int mt = 0; mt < 8; ++mt)
        af[mt] = *(const bf16x8*)&As[cur][((half * 4 + lkc) * 256 + wm0 + mt * 16 + li) * 8];
#pragma unroll
      for (int nt = 0; nt < 2; ++nt)
        bfr[nt] = *(const bf16x8*)&Bs[cur][((half * 4 + lkc) * 128 + wn0 + nt * 16 + li) * 8];
#pragma unroll
      for (int mt = 0; mt < 8; ++mt)
#pragma unroll
        for (int nt = 0; nt < 2; ++nt)
          acc[mt][nt] = __builtin_amdgcn_mfma_f32_16x16x32_bf16(
              af[mt], bfr[nt], acc[mt][nt], 0, 0, 0);
    }
    __syncthreads();               // vmcnt(0): prefetch flew under compute
    cur ^= 1;
  }
  // C/D layout: col=lane&15, row=(lane>>4)*4+reg (m89-verified)
  const int lq = lane >> 4;
#pragma unroll
  for (int mt = 0; mt < 8; ++mt) {
    int gm0 = row0 + wm0 + mt * 16 + lq * 4;
#pragma unroll
    for (int nt = 0; nt < 2; ++nt) {
      int gn = col0 + wn0 + nt * 16 + li;
      if (mode == 1) {
        if (gn < N1) {
          unsigned short* C1 = (unsigned short*)C1v;
#pragma unroll
          for (int r = 0; r < 4; ++r)
            C1[(size_t)(gm0 + r) * ld1 + gn] = f2bf(acc[mt][nt][r]);
        } else {
          unsigned short* C2 = (unsigned short*)C2v;
#pragma unroll
          for (int r = 0; r < 4; ++r)
            C2[(size_t)(gm0 + r) * ld2 + gn - N1] = f2bf(acc[mt][nt][r]);
        }
      } else if (mode == 2) {  // softplus(v + bias[col]) -> bf16
        unsigned short* C1 = (unsigned short*)C1v;
        float bb = bias[gn];
#pragma unroll
        for (int r = 0; r < 4; ++r) {
          float v = acc[mt][nt][r] + bb;
          C1[(size_t)(gm0 + r) * ld1 + gn] = f2bf(softplus_f(v));
        }
      } else {  // mode 3: fp32 plain store
        float* C1 = (float*)C1v;
#pragma unroll
        for (int r = 0; r < 4; ++r)
          C1[(size_t)(gm0 + r) * ld1 + gn] = acc[mt][nt][r];
      }
    }
  }
}

// ---------------------------------------------------------------------------
// Fused depthwise conv(4)+SiLU + x_proj partial (R13-proven, unchanged).
// ---------------------------------------------------------------------------
__global__ __launch_bounds__(256) void conv_xproj(
    const unsigned short* __restrict__ UPREB, const float* __restrict__ cw,
    const float* __restrict__ cb, const float* __restrict__ W,
    unsigned short* __restrict__ UB, float* __restrict__ XPART) {
  const int ks = blockIdx.x;        // 0..7
  const int rt = blockIdx.y;        // 0..127
  const int row0 = rt * 16;
  const int kbase = ks * 256;
  __shared__ unsigned short sU[16][256];  // 8 KB
  __shared__ float Bv[256 * 32];          // 32 KB
  const int tid = threadIdx.x;

  for (int i = tid; i < 256 * 32; i += 256)
    Bv[i] = W[(size_t)(kbase + (i >> 5)) * 32 + (i & 31)];

  {
    const int d = kbase + tid;
    const float w0 = cw[d * DCONV + 0], w1 = cw[d * DCONV + 1];
    const float w2 = cw[d * DCONV + 2], w3 = cw[d * DCONV + 3];
    const float bias = cb[d];
    float x0, x1, x2;
    if ((row0 & (LSEQ - 1)) == 0) {
      x0 = x1 = x2 = 0.f;
    } else {
      x0 = bf2f(UPREB[(size_t)(row0 - 3) * DINNER + d]);
      x1 = bf2f(UPREB[(size_t)(row0 - 2) * DINNER + d]);
      x2 = bf2f(UPREB[(size_t)(row0 - 1) * DINNER + d]);
    }
    for (int r = 0; r < 16; ++r) {
      float x3 = bf2f(UPREB[(size_t)(row0 + r) * DINNER + d]);
      float a = bias + x0 * w0 + x1 * w1 + x2 * w2 + x3 * w3;
      float u = a / (1.f + __expf(-a));
      unsigned short ub = f2bf(u);
      sU[r][tid] = ub;
      UB[(size_t)(row0 + r) * DINNER + d] = ub;
      x0 = x1; x1 = x2; x2 = x3;
    }
  }
  __syncthreads();

  // x_proj partial: C[16][32] = sU[16][256] @ W[256][32]; 8 groups x 2 rows
  const int col = tid & 31, rg = tid >> 5;
  float acc[2] = {};
  for (int k = 0; k < 256; k += 2) {
    float b0 = Bv[k * 32 + col], b1 = Bv[(k + 1) * 32 + col];
#pragma unroll
    for (int rr = 0; rr < 2; ++rr) {
      ushort2 uv = *(const ushort2*)&sU[rg * 2 + rr][k];
      acc[rr] += bf2f(uv.x) * b0 + bf2f(uv.y) * b1;
    }
  }
#pragma unroll
  for (int rr = 0; rr < 2; ++rr)
    XPART[(size_t)ks * NROWS * 32 + (size_t)(row0 + rg * 2 + rr) * 32 + col] = acc[rr];
}

// ---------------------------------------------------------------------------
// Scan pass 1 + inline x_proj reduce (R13-proven, R1 form: bf16 DELTAB).
// ---------------------------------------------------------------------------
__global__ __launch_bounds__(256) void scan_pass1(
    const unsigned short* __restrict__ DELTAB, const unsigned short* __restrict__ UB,
    const float* __restrict__ XPART, float* __restrict__ BCb,
    const float* __restrict__ A_log,
    float* __restrict__ PBUF, float* __restrict__ HBUF) {
  const int bx = blockIdx.x;
  const int b = bx >> 8;
  const int c = (bx >> 3) & (NCHUNK - 1);
  const int d = ((bx & 7) << 8) + threadIdx.x;
  const int l0 = c * LCHUNK;
  __shared__ float sB[LCHUNK * DSTATE];
#pragma unroll
  for (int i = 0; i < 2; ++i) {
    int e = threadIdx.x + i * 256;       // 32 rows x 16 cols
    int row = e >> 4, col = e & 15;
    size_t base = (size_t)(b * LSEQ + l0 + row) * 32 + col;
    float s = 0.f;
#pragma unroll
    for (int ks = 0; ks < 8; ++ks) s += XPART[(size_t)ks * NROWS * 32 + base];
    sB[e] = s;
  }
  if ((bx & 7) == 0) {
#pragma unroll
    for (int i = 0; i < 4; ++i) {
      int e = threadIdx.x + i * 256;     // 32 rows x 32 cols
      int row = e >> 5, col = e & 31;
      size_t base = (size_t)(b * LSEQ + l0 + row) * 32 + col;
      float s = 0.f;
#pragma unroll
      for (int ks = 0; ks < 8; ++ks) s += XPART[(size_t)ks * NROWS * 32 + base];
      BCb[base] = s;
    }
  }
  float Avv[DSTATE];
#pragma unroll
  for (int n = 0; n < DSTATE; ++n) Avv[n] = -__expf(A_log[d * DSTATE + n]);
  float h[DSTATE], P[DSTATE];
#pragma unroll
  for (int n = 0; n < DSTATE; ++n) { h[n] = 0.f; P[n] = 1.f; }
  __syncthreads();
  for (int lc = 0; lc < LCHUNK; ++lc) {
    size_t off = ((size_t)(b * LSEQ + l0 + lc)) * DINNER + d;
    float delta = bf2f(DELTAB[off]);
    float du = delta * bf2f(UB[off]);
#pragma unroll
    for (int n = 0; n < DSTATE; ++n) {
      float dA = __expf(delta * Avv[n]);
      P[n] *= dA;
      h[n] = dA * h[n] + du * sB[lc * DSTATE + n];
    }
  }
  size_t base = ((size_t)(b * NCHUNK + c)) * DSTATE * DINNER + d;
#pragma unroll
  for (int n = 0; n < DSTATE; ++n) {
    PBUF[base + (size_t)n * DINNER] = P[n];
    HBUF[base + (size_t)n * DINNER] = h[n];
  }
}

// ---------------------------------------------------------------------------
// Scan combine: sequential prefix across 32 chunks per (b,n,d).
// ---------------------------------------------------------------------------
__global__ __launch_bounds__(256) void scan_combine(
    const float* __restrict__ PBUF, float* __restrict__ HBUF) {
  const int bx = blockIdx.x;
  const int b = bx >> 7;
  const int n = (bx >> 3) & (DSTATE - 1);
  const int d = ((bx & 7) << 8) + threadIdx.x;
  float h = 0.f;
  for (int c = 0; c < NCHUNK; ++c) {
    size_t idx = (((size_t)(b * NCHUNK + c)) * DSTATE + n) * DINNER + d;
    float p = PBUF[idx];
    float hl = HBUF[idx];
    HBUF[idx] = h;
    h = p * h + hl;
  }
}

// ---------------------------------------------------------------------------
// Scan pass 2: rescan from incoming state; y = C.h + u*D, gate silu(res),
// emit bf16 Y.
// ---------------------------------------------------------------------------
__global__ __launch_bounds__(256) void scan_pass2(
    const unsigned short* __restrict__ DELTAB, const unsigned short* __restrict__ UB,
    const float* __restrict__ BC, const float* __restrict__ HBUF,
    const float* __restrict__ A_log, const float* __restrict__ D_param,
    const unsigned short* __restrict__ RESB, unsigned short* __restrict__ YB) {
  const int bx = blockIdx.x;
  const int b = bx >> 8;
  const int c = (bx >> 3) & (NCHUNK - 1);
  const int d = ((bx & 7) << 8) + threadIdx.x;
  const int l0 = c * LCHUNK;
  __shared__ float sBC[LCHUNK * 32];
#pragma unroll
  for (int i = 0; i < 4; ++i) {
    int e = threadIdx.x + i * 256;
    sBC[e] = BC[((size_t)(b * LSEQ + l0 + (e >> 5))) * 32 + (e & 31)];
  }
  float Avv[DSTATE];
#pragma unroll
  for (int n = 0; n < DSTATE; ++n) Avv[n] = -__expf(A_log[d * DSTATE + n]);
  const float Dp = D_param[d];
  float h[DSTATE];
  size_t base = ((size_t)(b * NCHUNK + c)) * DSTATE * DINNER + d;
#pragma unroll
  for (int n = 0; n < DSTATE; ++n) h[n] = HBUF[base + (size_t)n * DINNER];
  __syncthreads();
  for (int lc = 0; lc < LCHUNK; ++lc) {
    size_t off = ((size_t)(b * LSEQ + l0 + lc)) * DINNER + d;
    float delta = bf2f(DELTAB[off]);
    float uu = bf2f(UB[off]);
    float du = delta * uu;
    float y = 0.f;
#pragma unroll
    for (int n = 0; n < DSTATE; ++n) {
      float dA = __expf(delta * Avv[n]);
      h[n] = dA * h[n] + du * sBC[lc * 32 + n];
      y += h[n] * sBC[lc * 32 + 16 + n];
    }
    y += uu * Dp;
    float r = bf2f(RESB[off]);
    YB[off] = f2bf(y * (r / (1.f + __expf(-r))));
  }
}

// ---------------------------------------------------------------------------
extern "C" void kernel_launch(void* const* d_in, const int* in_sizes, int n_in,
                              void* d_out, int out_size, void* d_ws, size_t ws_size,
                              hipStream_t stream) {
  const float* x       = (const float*)d_in[0];
  const float* w_in    = (const float*)d_in[1];
  const float* conv_w  = (const float*)d_in[2];
  const float* conv_b  = (const float*)d_in[3];
  const float* xproj_w = (const float*)d_in[4];
  const float* dt_w    = (const float*)d_in[5];
  const float* dt_b    = (const float*)d_in[6];
  const float* A_log   = (const float*)d_in[7];
  const float* D_par   = (const float*)d_in[8];
  const float* out_w   = (const float*)d_in[9];
  float* out = (float*)d_out;

  char* ws = (char*)d_ws;
  const size_t MB = 1024 * 1024;
  // bf16 activation buffers (R1-proven layout)
  unsigned short* UPREB  = (unsigned short*)(ws + 0 * MB);   // 8 MB (dead after conv_xproj)
  unsigned short* RESB   = (unsigned short*)(ws + 8 * MB);   // 8 MB (dead after scan)
  unsigned short* UB     = (unsigned short*)(ws + 16 * MB);  // 8 MB
  unsigned short* DELTAB = (unsigned short*)(ws + 24 * MB);  // 8 MB
  unsigned short* YB     = (unsigned short*)(ws + 32 * MB);  // 8 MB
  unsigned short* XB     = (unsigned short*)(ws + 40 * MB);  // 4 MB (dead after in_proj)
  unsigned short* WINB   = (unsigned short*)(ws + 44 * MB);  // 8 MB (dead after in_proj)
  unsigned short* DTWB   = (unsigned short*)(ws + 52 * MB);  // 8 MB (dead after dt_proj)
  unsigned short* OWB    = (unsigned short*)(ws + 60 * MB);  // 4 MB (live to end)
  // overlays (first written strictly after underlying buffer dies)
  float* PBUF  = (float*)(ws + 0 * MB);                 // 8 MB over UPREB (w: pass1)
  float* HBUF  = (float*)(ws + 40 * MB);                // 8 MB over XB+WINB[0:4] (w: pass1)
  float* BCb   = (float*)(ws + 48 * MB);                // 256 KB over WINB[4:] (w: pass1)
  float* XPART = (float*)(ws + 48 * MB + 512 * 1024);   // 2 MB over WINB[4:] (w: conv_xproj)
  // footprint: 64 MB

  // input conversions
  cvt_all<<<dim3(12288), dim3(256), 0, stream>>>(
      x, w_in, dt_w, out_w, XB, WINB, DTWB, OWB);
  // in_proj: XB(2048x1024) x WINB(4096x1024)^T -> UPREB | RESB bf16
  // 256x128 tile: grid 32x8 = 256 blocks
  mfma_gemm_nt<<<dim3(2 * DINNER / 128, NROWS / 256, 1), dim3(512), 0, stream>>>(
      XB, DMODEL, WINB, DMODEL, UPREB, DINNER, RESB, DINNER, DINNER,
      nullptr, DMODEL, 1);
  // fused conv+silu+x_proj partial -> UB, XPART (16-row tiles, 1024 blocks)
  conv_xproj<<<dim3(8, NROWS / 16), dim3(256), 0, stream>>>(
      UPREB, conv_w, conv_b, xproj_w, UB, XPART);
  // dt_proj: UB x DTWB^T, softplus(+dt_b) -> DELTAB bf16 (unsplit, 128 blocks)
  mfma_gemm_nt<<<dim3(DINNER / 128, NROWS / 256, 1), dim3(512), 0, stream>>>(
      UB, DINNER, DTWB, DINNER, DELTAB, DINNER, nullptr, 0, DINNER,
      dt_b, DINNER, 2);
  // chunked selective scan (pass1 folds the x_proj reduce)
  scan_pass1<<<dim3(BATCH * NCHUNK * (DINNER / 256)), dim3(256), 0, stream>>>(
      DELTAB, UB, XPART, BCb, A_log, PBUF, HBUF);
  scan_combine<<<dim3(BATCH * DSTATE * (DINNER / 256)), dim3(256), 0, stream>>>(PBUF, HBUF);
  scan_pass2<<<dim3(BATCH * NCHUNK * (DINNER / 256)), dim3(256), 0, stream>>>(
      DELTAB, UB, BCb, HBUF, A_log, D_par, RESB, YB);
  // out_proj: YB(2048x2048) x OWB(1024x2048)^T -> out fp32 (unsplit, 64 blocks)
  mfma_gemm_nt<<<dim3(DMODEL / 128, NROWS / 256, 1), dim3(512), 0, stream>>>(
      YB, DINNER, OWB, DINNER, out, DMODEL, nullptr, 0, DMODEL,
      nullptr, DINNER, 3);
}

// Round 4
// 320.180 us; speedup vs baseline: 1.1978x; 1.1978x over previous
//
#include <hip/hip_runtime.h>
#include <math.h>

// Problem constants
#define BATCH   2
#define LSEQ    1024
#define DMODEL  1024
#define DSTATE  16
#define DCONV   4
#define DINNER  2048
#define NROWS   (BATCH * LSEQ)   // 2048

#define LCHUNK  32
#define NCHUNK  32

typedef short  bf16x8 __attribute__((ext_vector_type(8)));
typedef float  f32x4  __attribute__((ext_vector_type(4)));

__device__ __forceinline__ unsigned short f2bf(float f) {
  unsigned int u = __builtin_bit_cast(unsigned int, f);
  u = (u + 0x7fffu + ((u >> 16) & 1u)) >> 16;   // RNE
  return (unsigned short)u;
}
__device__ __forceinline__ float bf2f(unsigned short h) {
  return __builtin_bit_cast(float, (unsigned int)h << 16);
}

__device__ __forceinline__ float softplus_f(float v) {
  return (v > 20.f) ? v : __logf(1.f + __expf(v));
}

template <int N>
__device__ __forceinline__ void s_waitcnt_vm() {
  if constexpr (N == 0)       asm volatile("s_waitcnt vmcnt(0)" ::: "memory");
  else if constexpr (N == 3)  asm volatile("s_waitcnt vmcnt(3)" ::: "memory");
  else if constexpr (N == 4)  asm volatile("s_waitcnt vmcnt(4)" ::: "memory");
  else if constexpr (N == 6)  asm volatile("s_waitcnt vmcnt(6)" ::: "memory");
  else if constexpr (N == 8)  asm volatile("s_waitcnt vmcnt(8)" ::: "memory");
  else if constexpr (N == 12) asm volatile("s_waitcnt vmcnt(12)" ::: "memory");
}

// ---------------------------------------------------------------------------
// Fused input conversion (R13-proven). 4 regions; no zeroing (no atomics).
// ---------------------------------------------------------------------------
__device__ __forceinline__ void cvt_ew_body(const float* __restrict__ s,
                                            unsigned short* __restrict__ d,
                                            int blk, int tid) {
  int i = blk * 256 + tid;
  float4 v = ((const float4*)s)[i];
  ushort4 o;
  o.x = f2bf(v.x); o.y = f2bf(v.y); o.z = f2bf(v.z); o.w = f2bf(v.w);
  ((ushort4*)d)[i] = o;
}

__device__ __forceinline__ void cvt_tr_body(const float* __restrict__ s,
                                            unsigned short* __restrict__ d,
                                            int R, int C, int c0, int r0,
                                            int tid, float (*T)[33]) {
#pragma unroll
  for (int i = 0; i < 4; ++i) {
    int e = tid + i * 256;
    int r = e >> 5, c = e & 31;
    T[r][c] = s[(size_t)(r0 + r) * C + c0 + c];
  }
  __syncthreads();
#pragma unroll
  for (int i = 0; i < 4; ++i) {
    int e = tid + i * 256;
    int c = e >> 5, r = e & 31;
    d[(size_t)(c0 + c) * R + r0 + r] = f2bf(T[r][c]);
  }
}

__global__ __launch_bounds__(256) void cvt_all(
    const float* __restrict__ x, const float* __restrict__ w_in,
    const float* __restrict__ dt_w, const float* __restrict__ out_w,
    unsigned short* __restrict__ XB, unsigned short* __restrict__ WINB,
    unsigned short* __restrict__ DTWB, unsigned short* __restrict__ OWB) {
  __shared__ float T[32][33];
  const int bid = blockIdx.x;
  const int tid = threadIdx.x;
  if (bid < 2048) {
    cvt_ew_body(x, XB, bid, tid);
  } else if (bid < 6144) {
    int t = bid - 2048;
    cvt_tr_body(w_in, WINB, 1024, 4096, (t & 127) * 32, (t >> 7) * 32, tid, T);
  } else if (bid < 10240) {
    cvt_ew_body(dt_w, DTWB, bid - 6144, tid);
  } else {
    int t = bid - 10240;
    cvt_tr_body(out_w, OWB, 2048, 1024, (t & 31) * 32, (t >> 5) * 32, tid, T);
  }
}

// ---------------------------------------------------------------------------
// bf16 MFMA GEMM (NT), template<BM, BN>, BK=64, 512 threads, 8 waves as
// 2(row)x4(col); per-wave output (BM/2)x(BN/4).
// R4: COUNTED-VMCNT 3-BUFFER PIPELINE (T3+T4, learn_hip m218: counted vs
// drain0 = +38-73%). Per K-step:
//   stage(t+2) -> s_waitcnt vmcnt(2L) -> s_barrier -> MFMA(t)
//   -> lgkmcnt(0) -> s_barrier
// L = loads/thread/stage; 2 K-tiles of loads stay in flight ACROSS barriers;
// vmcnt never drains to 0 in the main loop (that drain was R0-R3's measured
// stall: MfmaUtil 6-10%, HBM ~10%, compute ~400cy < latency ~900cy).
// Raw __builtin_amdgcn_s_barrier (NOT __syncthreads — that emits vmcnt(0)).
// sched_barrier(0) pins stage-issue / waitcnt / compute order (rule #18).
// Buffer overwrite hazard: stage at iter t targets buf (t+2)%3, last read by
// compute(t-1); the lgkmcnt(0)+barrier at end of t-1 guards it.
// R2 lesson: NO fp32 atomics (~7 µs per million). No split-K anywhere; all
// grids are 256 blocks by tile choice.
// Epilogue modes: 1 = bf16 col<N1 -> C1 else C2  [in_proj u|res]
//                 2 = softplus(v+bias[col]) bf16 [dt_proj]
//                 3 = fp32 plain store           [out_proj]
// NOTE (R8/R11): NO inter-block coordination inside kernels.
// ---------------------------------------------------------------------------
template <int BM, int BN>
__global__ __launch_bounds__(512) void mfma_gemm_nt(
    const unsigned short* __restrict__ A, int lda,
    const unsigned short* __restrict__ Bt, int ldb,
    void* __restrict__ C1v, int ld1,
    void* __restrict__ C2v, int ld2, int N1,
    const float* __restrict__ bias,
    int KS, int mode) {
  constexpr int MT = BM / 32;          // M MFMA tiles per wave
  constexpr int NT = BN / 64;          // N MFMA tiles per wave
  constexpr int LA = BM / 64;          // A-stage loads per thread
  constexpr int LB = BN / 64;          // B-stage loads per thread
  constexpr int L  = LA + LB;
  __shared__ unsigned short As[3][8 * BM * 8];  // [buf][kc][row][8]
  __shared__ unsigned short Bs[3][8 * BN * 8];  // [buf][kc][col][8]
  const int tid  = threadIdx.x;
  const int wave = tid >> 6;        // 0..7
  const int lane = tid & 63;
  // bijective XCD swizzle (total % 8 == 0 for all our grids)
  const int total = gridDim.x * gridDim.y;
  const int lin = blockIdx.y * gridDim.x + blockIdx.x;
  const int wg = (lin & 7) * (total >> 3) + (lin >> 3);
  const int row0 = (wg / gridDim.x) * BM;
  const int col0 = (wg % gridDim.x) * BN;
  const int wm0 = (wave >> 2) * (BM / 2);
  const int wn0 = (wave & 3) * (BN / 4);

  f32x4 acc[MT][NT];
#pragma unroll
  for (int i = 0; i < MT; ++i)
#pragma unroll
    for (int j = 0; j < NT; ++j) acc[i][j] = (f32x4){0.f, 0.f, 0.f, 0.f};

  const int lkc = lane >> 4, li = lane & 15;
  const int nsteps = KS >> 6;

  auto stage = [&](int buf, int k0) {
#pragma unroll
    for (int it = 0; it < LA; ++it) {
      int s = it * 512 + tid;          // 0..8*BM-1 A slots (16B each)
      int kc = s / BM, r = s % BM;     // BM pow2 -> shifts
      __builtin_amdgcn_global_load_lds(
          (const __attribute__((address_space(1))) void*)(A + (size_t)(row0 + r) * lda + k0 + kc * 8),
          (__attribute__((address_space(3))) void*)(&As[buf][s * 8]), 16, 0, 0);
    }
#pragma unroll
    for (int it = 0; it < LB; ++it) {
      int s = it * 512 + tid;          // 0..8*BN-1 B slots
      int kc = s / BN, r = s % BN;
      __builtin_amdgcn_global_load_lds(
          (const __attribute__((address_space(1))) void*)(Bt + (size_t)(col0 + r) * ldb + k0 + kc * 8),
          (__attribute__((address_space(3))) void*)(&Bs[buf][s * 8]), 16, 0, 0);
    }
  };

  stage(0, 0);
  stage(1, 64);
  for (int t = 0; t < nsteps; ++t) {
    const int cur = t % 3;
    if (t + 2 < nsteps) stage((t + 2) % 3, (t + 2) << 6);
    __builtin_amdgcn_sched_barrier(0);
    if (t + 2 < nsteps)      s_waitcnt_vm<2 * L>();   // tile t landed; t+1,t+2 in flight
    else if (t + 1 < nsteps) s_waitcnt_vm<L>();
    else                     s_waitcnt_vm<0>();
    __builtin_amdgcn_s_barrier();
    __builtin_amdgcn_sched_barrier(0);
#pragma unroll
    for (int half = 0; half < 2; ++half) {
      bf16x8 af[MT], bfr[NT];
#pragma unroll
      for (int mt = 0; mt < MT; ++mt)
        af[mt] = *(const bf16x8*)&As[cur][((half * 4 + lkc) * BM + wm0 + mt * 16 + li) * 8];
#pragma unroll
      for (int nt = 0; nt < NT; ++nt)
        bfr[nt] = *(const bf16x8*)&Bs[cur][((half * 4 + lkc) * BN + wn0 + nt * 16 + li) * 8];
#pragma unroll
      for (int mt = 0; mt < MT; ++mt)
#pragma unroll
        for (int nt = 0; nt < NT; ++nt)
          acc[mt][nt] = __builtin_amdgcn_mfma_f32_16x16x32_bf16(
              af[mt], bfr[nt], acc[mt][nt], 0, 0, 0);
    }
    __builtin_amdgcn_sched_barrier(0);
    asm volatile("s_waitcnt lgkmcnt(0)" ::: "memory");  // ds_reads of buf done
    __builtin_amdgcn_s_barrier();                       // no vmcnt drain!
  }
  // C/D layout: col=lane&15, row=(lane>>4)*4+reg (m89-verified)
  const int lq = lane >> 4;
#pragma unroll
  for (int mt = 0; mt < MT; ++mt) {
    int gm0 = row0 + wm0 + mt * 16 + lq * 4;
#pragma unroll
    for (int nt = 0; nt < NT; ++nt) {
      int gn = col0 + wn0 + nt * 16 + li;
      if (mode == 1) {
        if (gn < N1) {
          unsigned short* C1 = (unsigned short*)C1v;
#pragma unroll
          for (int r = 0; r < 4; ++r)
            C1[(size_t)(gm0 + r) * ld1 + gn] = f2bf(acc[mt][nt][r]);
        } else {
          unsigned short* C2 = (unsigned short*)C2v;
#pragma unroll
          for (int r = 0; r < 4; ++r)
            C2[(size_t)(gm0 + r) * ld2 + gn - N1] = f2bf(acc[mt][nt][r]);
        }
      } else if (mode == 2) {  // softplus(v + bias[col]) -> bf16
        unsigned short* C1 = (unsigned short*)C1v;
        float bb = bias[gn];
#pragma unroll
        for (int r = 0; r < 4; ++r) {
          float v = acc[mt][nt][r] + bb;
          C1[(size_t)(gm0 + r) * ld1 + gn] = f2bf(softplus_f(v));
        }
      } else {  // mode 3: fp32 plain store
        float* C1 = (float*)C1v;
#pragma unroll
        for (int r = 0; r < 4; ++r)
          C1[(size_t)(gm0 + r) * ld1 + gn] = acc[mt][nt][r];
      }
    }
  }
}

// ---------------------------------------------------------------------------
// Fused depthwise conv(4)+SiLU + x_proj partial (R13-proven, unchanged).
// ---------------------------------------------------------------------------
__global__ __launch_bounds__(256) void conv_xproj(
    const unsigned short* __restrict__ UPREB, const float* __restrict__ cw,
    const float* __restrict__ cb, const float* __restrict__ W,
    unsigned short* __restrict__ UB, float* __restrict__ XPART) {
  const int ks = blockIdx.x;        // 0..7
  const int rt = blockIdx.y;        // 0..127
  const int row0 = rt * 16;
  const int kbase = ks * 256;
  __shared__ unsigned short sU[16][256];  // 8 KB
  __shared__ float Bv[256 * 32];          // 32 KB
  const int tid = threadIdx.x;

  for (int i = tid; i < 256 * 32; i += 256)
    Bv[i] = W[(size_t)(kbase + (i >> 5)) * 32 + (i & 31)];

  {
    const int d = kbase + tid;
    const float w0 = cw[d * DCONV + 0], w1 = cw[d * DCONV + 1];
    const float w2 = cw[d * DCONV + 2], w3 = cw[d * DCONV + 3];
    const float bias = cb[d];
    float x0, x1, x2;
    if ((row0 & (LSEQ - 1)) == 0) {
      x0 = x1 = x2 = 0.f;
    } else {
      x0 = bf2f(UPREB[(size_t)(row0 - 3) * DINNER + d]);
      x1 = bf2f(UPREB[(size_t)(row0 - 2) * DINNER + d]);
      x2 = bf2f(UPREB[(size_t)(row0 - 1) * DINNER + d]);
    }
    for (int r = 0; r < 16; ++r) {
      float x3 = bf2f(UPREB[(size_t)(row0 + r) * DINNER + d]);
      float a = bias + x0 * w0 + x1 * w1 + x2 * w2 + x3 * w3;
      float u = a / (1.f + __expf(-a));
      unsigned short ub = f2bf(u);
      sU[r][tid] = ub;
      UB[(size_t)(row0 + r) * DINNER + d] = ub;
      x0 = x1; x1 = x2; x2 = x3;
    }
  }
  __syncthreads();

  // x_proj partial: C[16][32] = sU[16][256] @ W[256][32]; 8 groups x 2 rows
  const int col = tid & 31, rg = tid >> 5;
  float acc[2] = {};
  for (int k = 0; k < 256; k += 2) {
    float b0 = Bv[k * 32 + col], b1 = Bv[(k + 1) * 32 + col];
#pragma unroll
    for (int rr = 0; rr < 2; ++rr) {
      ushort2 uv = *(const ushort2*)&sU[rg * 2 + rr][k];
      acc[rr] += bf2f(uv.x) * b0 + bf2f(uv.y) * b1;
    }
  }
#pragma unroll
  for (int rr = 0; rr < 2; ++rr)
    XPART[(size_t)ks * NROWS * 32 + (size_t)(row0 + rg * 2 + rr) * 32 + col] = acc[rr];
}

// ---------------------------------------------------------------------------
// Scan pass 1 + inline x_proj reduce (R13-proven).
// ---------------------------------------------------------------------------
__global__ __launch_bounds__(256) void scan_pass1(
    const unsigned short* __restrict__ DELTAB, const unsigned short* __restrict__ UB,
    const float* __restrict__ XPART, float* __restrict__ BCb,
    const float* __restrict__ A_log,
    float* __restrict__ PBUF, float* __restrict__ HBUF) {
  const int bx = blockIdx.x;
  const int b = bx >> 8;
  const int c = (bx >> 3) & (NCHUNK - 1);
  const int d = ((bx & 7) << 8) + threadIdx.x;
  const int l0 = c * LCHUNK;
  __shared__ float sB[LCHUNK * DSTATE];
#pragma unroll
  for (int i = 0; i < 2; ++i) {
    int e = threadIdx.x + i * 256;       // 32 rows x 16 cols
    int row = e >> 4, col = e & 15;
    size_t base = (size_t)(b * LSEQ + l0 + row) * 32 + col;
    float s = 0.f;
#pragma unroll
    for (int ks = 0; ks < 8; ++ks) s += XPART[(size_t)ks * NROWS * 32 + base];
    sB[e] = s;
  }
  if ((bx & 7) == 0) {
#pragma unroll
    for (int i = 0; i < 4; ++i) {
      int e = threadIdx.x + i * 256;     // 32 rows x 32 cols
      int row = e >> 5, col = e & 31;
      size_t base = (size_t)(b * LSEQ + l0 + row) * 32 + col;
      float s = 0.f;
#pragma unroll
      for (int ks = 0; ks < 8; ++ks) s += XPART[(size_t)ks * NROWS * 32 + base];
      BCb[base] = s;
    }
  }
  float Avv[DSTATE];
#pragma unroll
  for (int n = 0; n < DSTATE; ++n) Avv[n] = -__expf(A_log[d * DSTATE + n]);
  float h[DSTATE], P[DSTATE];
#pragma unroll
  for (int n = 0; n < DSTATE; ++n) { h[n] = 0.f; P[n] = 1.f; }
  __syncthreads();
  for (int lc = 0; lc < LCHUNK; ++lc) {
    size_t off = ((size_t)(b * LSEQ + l0 + lc)) * DINNER + d;
    float delta = bf2f(DELTAB[off]);
    float du = delta * bf2f(UB[off]);
#pragma unroll
    for (int n = 0; n < DSTATE; ++n) {
      float dA = __expf(delta * Avv[n]);
      P[n] *= dA;
      h[n] = dA * h[n] + du * sB[lc * DSTATE + n];
    }
  }
  size_t base = ((size_t)(b * NCHUNK + c)) * DSTATE * DINNER + d;
#pragma unroll
  for (int n = 0; n < DSTATE; ++n) {
    PBUF[base + (size_t)n * DINNER] = P[n];
    HBUF[base + (size_t)n * DINNER] = h[n];
  }
}

// ---------------------------------------------------------------------------
// Scan combine: sequential prefix across 32 chunks per (b,n,d).
// ---------------------------------------------------------------------------
__global__ __launch_bounds__(256) void scan_combine(
    const float* __restrict__ PBUF, float* __restrict__ HBUF) {
  const int bx = blockIdx.x;
  const int b = bx >> 7;
  const int n = (bx >> 3) & (DSTATE - 1);
  const int d = ((bx & 7) << 8) + threadIdx.x;
  float h = 0.f;
  for (int c = 0; c < NCHUNK; ++c) {
    size_t idx = (((size_t)(b * NCHUNK + c)) * DSTATE + n) * DINNER + d;
    float p = PBUF[idx];
    float hl = HBUF[idx];
    HBUF[idx] = h;
    h = p * h + hl;
  }
}

// ---------------------------------------------------------------------------
// Scan pass 2: rescan from incoming state; y = C.h + u*D, gate silu(res),
// emit bf16 Y.
// ---------------------------------------------------------------------------
__global__ __launch_bounds__(256) void scan_pass2(
    const unsigned short* __restrict__ DELTAB, const unsigned short* __restrict__ UB,
    const float* __restrict__ BC, const float* __restrict__ HBUF,
    const float* __restrict__ A_log, const float* __restrict__ D_param,
    const unsigned short* __restrict__ RESB, unsigned short* __restrict__ YB) {
  const int bx = blockIdx.x;
  const int b = bx >> 8;
  const int c = (bx >> 3) & (NCHUNK - 1);
  const int d = ((bx & 7) << 8) + threadIdx.x;
  const int l0 = c * LCHUNK;
  __shared__ float sBC[LCHUNK * 32];
#pragma unroll
  for (int i = 0; i < 4; ++i) {
    int e = threadIdx.x + i * 256;
    sBC[e] = BC[((size_t)(b * LSEQ + l0 + (e >> 5))) * 32 + (e & 31)];
  }
  float Avv[DSTATE];
#pragma unroll
  for (int n = 0; n < DSTATE; ++n) Avv[n] = -__expf(A_log[d * DSTATE + n]);
  const float Dp = D_param[d];
  float h[DSTATE];
  size_t base = ((size_t)(b * NCHUNK + c)) * DSTATE * DINNER + d;
#pragma unroll
  for (int n = 0; n < DSTATE; ++n) h[n] = HBUF[base + (size_t)n * DINNER];
  __syncthreads();
  for (int lc = 0; lc < LCHUNK; ++lc) {
    size_t off = ((size_t)(b * LSEQ + l0 + lc)) * DINNER + d;
    float delta = bf2f(DELTAB[off]);
    float uu = bf2f(UB[off]);
    float du = delta * uu;
    float y = 0.f;
#pragma unroll
    for (int n = 0; n < DSTATE; ++n) {
      float dA = __expf(delta * Avv[n]);
      h[n] = dA * h[n] + du * sBC[lc * 32 + n];
      y += h[n] * sBC[lc * 32 + 16 + n];
    }
    y += uu * Dp;
    float r = bf2f(RESB[off]);
    YB[off] = f2bf(y * (r / (1.f + __expf(-r))));
  }
}

// ---------------------------------------------------------------------------
extern "C" void kernel_launch(void* const* d_in, const int* in_sizes, int n_in,
                              void* d_out, int out_size, void* d_ws, size_t ws_size,
                              hipStream_t stream) {
  const float* x       = (const float*)d_in[0];
  const float* w_in    = (const float*)d_in[1];
  const float* conv_w  = (const float*)d_in[2];
  const float* conv_b  = (const float*)d_in[3];
  const float* xproj_w = (const float*)d_in[4];
  const float* dt_w    = (const float*)d_in[5];
  const float* dt_b    = (const float*)d_in[6];
  const float* A_log   = (const float*)d_in[7];
  const float* D_par   = (const float*)d_in[8];
  const float* out_w   = (const float*)d_in[9];
  float* out = (float*)d_out;

  char* ws = (char*)d_ws;
  const size_t MB = 1024 * 1024;
  // bf16 activation buffers (R1-proven layout)
  unsigned short* UPREB  = (unsigned short*)(ws + 0 * MB);   // 8 MB (dead after conv_xproj)
  unsigned short* RESB   = (unsigned short*)(ws + 8 * MB);   // 8 MB (dead after scan)
  unsigned short* UB     = (unsigned short*)(ws + 16 * MB);  // 8 MB
  unsigned short* DELTAB = (unsigned short*)(ws + 24 * MB);  // 8 MB
  unsigned short* YB     = (unsigned short*)(ws + 32 * MB);  // 8 MB
  unsigned short* XB     = (unsigned short*)(ws + 40 * MB);  // 4 MB (dead after in_proj)
  unsigned short* WINB   = (unsigned short*)(ws + 44 * MB);  // 8 MB (dead after in_proj)
  unsigned short* DTWB   = (unsigned short*)(ws + 52 * MB);  // 8 MB (dead after dt_proj)
  unsigned short* OWB    = (unsigned short*)(ws + 60 * MB);  // 4 MB (live to end)
  // overlays (first written strictly after underlying buffer dies)
  float* PBUF  = (float*)(ws + 0 * MB);                 // 8 MB over UPREB (w: pass1)
  float* HBUF  = (float*)(ws + 40 * MB);                // 8 MB over XB+WINB[0:4] (w: pass1)
  float* BCb   = (float*)(ws + 48 * MB);                // 256 KB over WINB[4:] (w: pass1)
  float* XPART = (float*)(ws + 48 * MB + 512 * 1024);   // 2 MB over WINB[4:] (w: conv_xproj)
  // footprint: 64 MB

  // input conversions
  cvt_all<<<dim3(12288), dim3(256), 0, stream>>>(
      x, w_in, dt_w, out_w, XB, WINB, DTWB, OWB);
  // in_proj: XB(2048x1024) x WINB(4096x1024)^T -> UPREB | RESB bf16
  // 256x128 tile: grid (32, 8) = 256 blocks, K=1024 (16 steps)
  mfma_gemm_nt<256, 128><<<dim3(2 * DINNER / 128, NROWS / 256, 1), dim3(512), 0, stream>>>(
      XB, DMODEL, WINB, DMODEL, UPREB, DINNER, RESB, DINNER, DINNER,
      nullptr, DMODEL, 1);
  // fused conv+silu+x_proj partial -> UB, XPART (16-row tiles, 1024 blocks)
  conv_xproj<<<dim3(8, NROWS / 16), dim3(256), 0, stream>>>(
      UPREB, conv_w, conv_b, xproj_w, UB, XPART);
  // dt_proj: UB x DTWB^T, softplus(+dt_b) -> DELTAB bf16
  // 128x128 tile: grid (16, 16) = 256 blocks, K=2048 (32 steps)
  mfma_gemm_nt<128, 128><<<dim3(DINNER / 128, NROWS / 128, 1), dim3(512), 0, stream>>>(
      UB, DINNER, DTWB, DINNER, DELTAB, DINNER, nullptr, 0, DINNER,
      dt_b, DINNER, 2);
  // chunked selective scan (pass1 folds the x_proj reduce)
  scan_pass1<<<dim3(BATCH * NCHUNK * (DINNER / 256)), dim3(256), 0, stream>>>(
      DELTAB, UB, XPART, BCb, A_log, PBUF, HBUF);
  scan_combine<<<dim3(BATCH * DSTATE * (DINNER / 256)), dim3(256), 0, stream>>>(PBUF, HBUF);
  scan_pass2<<<dim3(BATCH * NCHUNK * (DINNER / 256)), dim3(256), 0, stream>>>(
      DELTAB, UB, BCb, HBUF, A_log, D_par, RESB, YB);
  // out_proj: YB(2048x2048) x OWB(1024x2048)^T -> out fp32
  // 128x64 tile: grid (16, 16) = 256 blocks, K=2048 (32 steps)
  mfma_gemm_nt<128, 64><<<dim3(DMODEL / 64, NROWS / 128, 1), dim3(512), 0, stream>>>(
      YB, DINNER, OWB, DINNER, out, DMODEL, nullptr, 0, DMODEL,
      nullptr, DINNER, 3);
}

// Round 5
// 304.561 us; speedup vs baseline: 1.2593x; 1.0513x over previous
//
#include <hip/hip_runtime.h>
#include <math.h>

// Problem constants
#define BATCH   2
#define LSEQ    1024
#define DMODEL  1024
#define DSTATE  16
#define DCONV   4
#define DINNER  2048
#define NROWS   (BATCH * LSEQ)   // 2048

#define LCHUNK  32
#define NCHUNK  32

typedef short  bf16x8 __attribute__((ext_vector_type(8)));
typedef float  f32x4  __attribute__((ext_vector_type(4)));

__device__ __forceinline__ unsigned short f2bf(float f) {
  unsigned int u = __builtin_bit_cast(unsigned int, f);
  u = (u + 0x7fffu + ((u >> 16) & 1u)) >> 16;   // RNE
  return (unsigned short)u;
}
__device__ __forceinline__ float bf2f(unsigned short h) {
  return __builtin_bit_cast(float, (unsigned int)h << 16);
}
__device__ __forceinline__ float softplus_f(float v) {
  return (v > 20.f) ? v : __logf(1.f + __expf(v));
}

// ---------------------------------------------------------------------------
// Fused input conversion (R13-proven). 4 regions; no zeroing (no atomics).
// ---------------------------------------------------------------------------
__device__ __forceinline__ void cvt_ew_body(const float* __restrict__ s,
                                            unsigned short* __restrict__ d,
                                            int blk, int tid) {
  int i = blk * 256 + tid;
  float4 v = ((const float4*)s)[i];
  ushort4 o;
  o.x = f2bf(v.x); o.y = f2bf(v.y); o.z = f2bf(v.z); o.w = f2bf(v.w);
  ((ushort4*)d)[i] = o;
}

__device__ __forceinline__ void cvt_tr_body(const float* __restrict__ s,
                                            unsigned short* __restrict__ d,
                                            int R, int C, int c0, int r0,
                                            int tid, float (*T)[33]) {
#pragma unroll
  for (int i = 0; i < 4; ++i) {
    int e = tid + i * 256;
    int r = e >> 5, c = e & 31;
    T[r][c] = s[(size_t)(r0 + r) * C + c0 + c];
  }
  __syncthreads();
#pragma unroll
  for (int i = 0; i < 4; ++i) {
    int e = tid + i * 256;
    int c = e >> 5, r = e & 31;
    d[(size_t)(c0 + c) * R + r0 + r] = f2bf(T[r][c]);
  }
}

__global__ __launch_bounds__(256) void cvt_all(
    const float* __restrict__ x, const float* __restrict__ w_in,
    const float* __restrict__ dt_w, const float* __restrict__ out_w,
    unsigned short* __restrict__ XB, unsigned short* __restrict__ WINB,
    unsigned short* __restrict__ DTWB, unsigned short* __restrict__ OWB) {
  __shared__ float T[32][33];
  const int bid = blockIdx.x;
  const int tid = threadIdx.x;
  if (bid < 2048) {
    cvt_ew_body(x, XB, bid, tid);
  } else if (bid < 6144) {
    int t = bid - 2048;
    cvt_tr_body(w_in, WINB, 1024, 4096, (t & 127) * 32, (t >> 7) * 32, tid, T);
  } else if (bid < 10240) {
    cvt_ew_body(dt_w, DTWB, bid - 6144, tid);
  } else {
    int t = bid - 10240;
    cvt_tr_body(out_w, OWB, 2048, 1024, (t & 31) * 32, (t >> 5) * 32, tid, T);
  }
}

// ---------------------------------------------------------------------------
// bf16 MFMA GEMM (NT) — the R1-proven 2-phase kernel, BM=128 x BN (template),
// BK=64, 512 threads, 8 waves 2(row)x4(col), LDS 16 + BN/8 KB single-buffer.
// R5 RATE-LAW (fit to R0/R1/R3/R4 + m97@4k): per-CU global_load_lds staging
// throughput ≈ 18 GB/s x (resident blocks/CU), INSENSITIVE to within-block
// pipeline depth (R4's 3-deep counted-vmcnt pipeline: exact null). So the
// lever is resident blocks at constant total staging: split-K with plain
// fp32 partial stores (NOT atomics — R2: ~7 µs per million atomicAdds).
// dt_proj: splitK=4 -> 1024 blocks = 4/CU (LDS 4x32=128 KB, 32 waves full).
// Epilogue modes: 1 = bf16 col<N1 -> C1 else C2   [in_proj u|res]
//                 3 = fp32 store to slab blockIdx.z (slab elems in N1)
// NOTE (R8/R11): NO inter-block coordination inside kernels.
// ---------------------------------------------------------------------------
template <int BN>
__global__ __launch_bounds__(512) void mfma_gemm_nt(
    const unsigned short* __restrict__ A, int lda,
    const unsigned short* __restrict__ Bt, int ldb,
    void* __restrict__ C1v, int ld1,
    void* __restrict__ C2v, int ld2, int N1,
    const float* __restrict__ bias,
    int KS, int mode) {
  constexpr int NT = BN / 64;                 // col MFMA tiles per wave
  __shared__ unsigned short As[8 * 128 * 8];  // 16 KB [kc][row][8]
  __shared__ unsigned short Bs[8 * BN * 8];   // BN/8 KB
  const int tid  = threadIdx.x;
  const int wave = tid >> 6;        // 0..7
  const int lane = tid & 63;
  const int linear = blockIdx.y * gridDim.x + blockIdx.x;
  const int xcd = linear & 7;
  const int pos = linear >> 3;
  const int row0 = (xcd * 2 + (pos & 1)) * 128;   // 16 M-panels (M=2048)
  const int col0 = (pos >> 1) * BN;
  const int wm0 = (wave >> 2) * 64;
  const int wn0 = (wave & 3) * (BN / 4);
  const int kb = blockIdx.z * KS;

  f32x4 acc[4][NT];
#pragma unroll
  for (int i = 0; i < 4; ++i)
#pragma unroll
    for (int j = 0; j < NT; ++j) acc[i][j] = (f32x4){0.f, 0.f, 0.f, 0.f};

  const int lkc = lane >> 4, li = lane & 15;
  for (int k0 = kb; k0 < kb + KS; k0 += 64) {
#pragma unroll
    for (int it = 0; it < 2; ++it) {
      int s = it * 512 + tid;        // 0..1023 A slots (16B each)
      int kc = s >> 7, r = s & 127;
      __builtin_amdgcn_global_load_lds(
          (const __attribute__((address_space(1))) void*)(A + (size_t)(row0 + r) * lda + k0 + kc * 8),
          (__attribute__((address_space(3))) void*)(&As[s * 8]), 16, 0, 0);
    }
#pragma unroll
    for (int it = 0; it < BN / 64; ++it) {
      int s = it * 512 + tid;        // 0..8*BN-1 B slots
      int kc = s / BN, r = s % BN;   // BN is pow2 -> shifts
      __builtin_amdgcn_global_load_lds(
          (const __attribute__((address_space(1))) void*)(Bt + (size_t)(col0 + r) * ldb + k0 + kc * 8),
          (__attribute__((address_space(3))) void*)(&Bs[s * 8]), 16, 0, 0);
    }
    __syncthreads();
#pragma unroll
    for (int half = 0; half < 2; ++half) {
      bf16x8 af[4], bfr[NT];
#pragma unroll
      for (int mt = 0; mt < 4; ++mt)
        af[mt] = *(const bf16x8*)&As[((half * 4 + lkc) * 128 + wm0 + mt * 16 + li) * 8];
#pragma unroll
      for (int nt = 0; nt < NT; ++nt)
        bfr[nt] = *(const bf16x8*)&Bs[((half * 4 + lkc) * BN + wn0 + nt * 16 + li) * 8];
#pragma unroll
      for (int mt = 0; mt < 4; ++mt)
#pragma unroll
        for (int nt = 0; nt < NT; ++nt)
          acc[mt][nt] = __builtin_amdgcn_mfma_f32_16x16x32_bf16(
              af[mt], bfr[nt], acc[mt][nt], 0, 0, 0);
    }
    __syncthreads();
  }
  // C/D layout: col=lane&15, row=(lane>>4)*4+reg (m89-verified)
  const int lq = lane >> 4;
#pragma unroll
  for (int mt = 0; mt < 4; ++mt) {
    int gm0 = row0 + wm0 + mt * 16 + lq * 4;
#pragma unroll
    for (int nt = 0; nt < NT; ++nt) {
      int gn = col0 + wn0 + nt * 16 + li;
      if (mode == 1) {
        if (gn < N1) {
          unsigned short* C1 = (unsigned short*)C1v;
#pragma unroll
          for (int r = 0; r < 4; ++r)
            C1[(size_t)(gm0 + r) * ld1 + gn] = f2bf(acc[mt][nt][r]);
        } else {
          unsigned short* C2 = (unsigned short*)C2v;
#pragma unroll
          for (int r = 0; r < 4; ++r)
            C2[(size_t)(gm0 + r) * ld2 + gn - N1] = f2bf(acc[mt][nt][r]);
        }
      } else {  // mode 3: fp32 plain store into partial slab blockIdx.z
        float* C1 = (float*)C1v + (size_t)blockIdx.z * (size_t)N1;
#pragma unroll
        for (int r = 0; r < 4; ++r)
          C1[(size_t)(gm0 + r) * ld1 + gn] = acc[mt][nt][r];
      }
    }
  }
}

// ---------------------------------------------------------------------------
// dt partial reduce: DELTAB = softplus(sum_z DT4[z] + dt_b[col]) -> bf16.
// 4M elems, float4 per thread, 4096 blocks.
// ---------------------------------------------------------------------------
__global__ __launch_bounds__(256) void dt_reduce(
    const float* __restrict__ P, const float* __restrict__ dtb,
    unsigned short* __restrict__ D) {
  const size_t SL = (size_t)NROWS * DINNER;       // 4M floats per slab
  size_t i4 = (size_t)blockIdx.x * 256 + threadIdx.x;
  float4 a = ((const float4*)P)[i4];
  float4 b = ((const float4*)(P + SL))[i4];
  float4 c = ((const float4*)(P + 2 * SL))[i4];
  float4 d = ((const float4*)(P + 3 * SL))[i4];
  int col = (int)((i4 * 4) & (DINNER - 1));
  float4 bb = *(const float4*)&dtb[col];
  ushort4 o;
  o.x = f2bf(softplus_f(a.x + b.x + c.x + d.x + bb.x));
  o.y = f2bf(softplus_f(a.y + b.y + c.y + d.y + bb.y));
  o.z = f2bf(softplus_f(a.z + b.z + c.z + d.z + bb.z));
  o.w = f2bf(softplus_f(a.w + b.w + c.w + d.w + bb.w));
  ((ushort4*)D)[i4] = o;
}

// ---------------------------------------------------------------------------
// out partial reduce: out = OUT2[0] + OUT2[1] (fp32). 2M elems, 2048 blocks.
// ---------------------------------------------------------------------------
__global__ __launch_bounds__(256) void out_reduce(
    const float* __restrict__ P, float* __restrict__ out) {
  const size_t SL = (size_t)NROWS * DMODEL;       // 2M floats per slab
  size_t i4 = (size_t)blockIdx.x * 256 + threadIdx.x;
  float4 a = ((const float4*)P)[i4];
  float4 b = ((const float4*)(P + SL))[i4];
  ((float4*)out)[i4] = make_float4(a.x + b.x, a.y + b.y, a.z + b.z, a.w + b.w);
}

// ---------------------------------------------------------------------------
// Fused depthwise conv(4)+SiLU + x_proj partial (R13-proven, unchanged).
// ---------------------------------------------------------------------------
__global__ __launch_bounds__(256) void conv_xproj(
    const unsigned short* __restrict__ UPREB, const float* __restrict__ cw,
    const float* __restrict__ cb, const float* __restrict__ W,
    unsigned short* __restrict__ UB, float* __restrict__ XPART) {
  const int ks = blockIdx.x;        // 0..7
  const int rt = blockIdx.y;        // 0..127
  const int row0 = rt * 16;
  const int kbase = ks * 256;
  __shared__ unsigned short sU[16][256];  // 8 KB
  __shared__ float Bv[256 * 32];          // 32 KB
  const int tid = threadIdx.x;

  for (int i = tid; i < 256 * 32; i += 256)
    Bv[i] = W[(size_t)(kbase + (i >> 5)) * 32 + (i & 31)];

  {
    const int d = kbase + tid;
    const float w0 = cw[d * DCONV + 0], w1 = cw[d * DCONV + 1];
    const float w2 = cw[d * DCONV + 2], w3 = cw[d * DCONV + 3];
    const float bias = cb[d];
    float x0, x1, x2;
    if ((row0 & (LSEQ - 1)) == 0) {
      x0 = x1 = x2 = 0.f;
    } else {
      x0 = bf2f(UPREB[(size_t)(row0 - 3) * DINNER + d]);
      x1 = bf2f(UPREB[(size_t)(row0 - 2) * DINNER + d]);
      x2 = bf2f(UPREB[(size_t)(row0 - 1) * DINNER + d]);
    }
    for (int r = 0; r < 16; ++r) {
      float x3 = bf2f(UPREB[(size_t)(row0 + r) * DINNER + d]);
      float a = bias + x0 * w0 + x1 * w1 + x2 * w2 + x3 * w3;
      float u = a / (1.f + __expf(-a));
      unsigned short ub = f2bf(u);
      sU[r][tid] = ub;
      UB[(size_t)(row0 + r) * DINNER + d] = ub;
      x0 = x1; x1 = x2; x2 = x3;
    }
  }
  __syncthreads();

  // x_proj partial: C[16][32] = sU[16][256] @ W[256][32]; 8 groups x 2 rows
  const int col = tid & 31, rg = tid >> 5;
  float acc[2] = {};
  for (int k = 0; k < 256; k += 2) {
    float b0 = Bv[k * 32 + col], b1 = Bv[(k + 1) * 32 + col];
#pragma unroll
    for (int rr = 0; rr < 2; ++rr) {
      ushort2 uv = *(const ushort2*)&sU[rg * 2 + rr][k];
      acc[rr] += bf2f(uv.x) * b0 + bf2f(uv.y) * b1;
    }
  }
#pragma unroll
  for (int rr = 0; rr < 2; ++rr)
    XPART[(size_t)ks * NROWS * 32 + (size_t)(row0 + rg * 2 + rr) * 32 + col] = acc[rr];
}

// ---------------------------------------------------------------------------
// Scan pass 1 + inline x_proj reduce (R13-proven).
// ---------------------------------------------------------------------------
__global__ __launch_bounds__(256) void scan_pass1(
    const unsigned short* __restrict__ DELTAB, const unsigned short* __restrict__ UB,
    const float* __restrict__ XPART, float* __restrict__ BCb,
    const float* __restrict__ A_log,
    float* __restrict__ PBUF, float* __restrict__ HBUF) {
  const int bx = blockIdx.x;
  const int b = bx >> 8;
  const int c = (bx >> 3) & (NCHUNK - 1);
  const int d = ((bx & 7) << 8) + threadIdx.x;
  const int l0 = c * LCHUNK;
  __shared__ float sB[LCHUNK * DSTATE];
#pragma unroll
  for (int i = 0; i < 2; ++i) {
    int e = threadIdx.x + i * 256;       // 32 rows x 16 cols
    int row = e >> 4, col = e & 15;
    size_t base = (size_t)(b * LSEQ + l0 + row) * 32 + col;
    float s = 0.f;
#pragma unroll
    for (int ks = 0; ks < 8; ++ks) s += XPART[(size_t)ks * NROWS * 32 + base];
    sB[e] = s;
  }
  if ((bx & 7) == 0) {
#pragma unroll
    for (int i = 0; i < 4; ++i) {
      int e = threadIdx.x + i * 256;     // 32 rows x 32 cols
      int row = e >> 5, col = e & 31;
      size_t base = (size_t)(b * LSEQ + l0 + row) * 32 + col;
      float s = 0.f;
#pragma unroll
      for (int ks = 0; ks < 8; ++ks) s += XPART[(size_t)ks * NROWS * 32 + base];
      BCb[base] = s;
    }
  }
  float Avv[DSTATE];
#pragma unroll
  for (int n = 0; n < DSTATE; ++n) Avv[n] = -__expf(A_log[d * DSTATE + n]);
  float h[DSTATE], P[DSTATE];
#pragma unroll
  for (int n = 0; n < DSTATE; ++n) { h[n] = 0.f; P[n] = 1.f; }
  __syncthreads();
  for (int lc = 0; lc < LCHUNK; ++lc) {
    size_t off = ((size_t)(b * LSEQ + l0 + lc)) * DINNER + d;
    float delta = bf2f(DELTAB[off]);
    float du = delta * bf2f(UB[off]);
#pragma unroll
    for (int n = 0; n < DSTATE; ++n) {
      float dA = __expf(delta * Avv[n]);
      P[n] *= dA;
      h[n] = dA * h[n] + du * sB[lc * DSTATE + n];
    }
  }
  size_t base = ((size_t)(b * NCHUNK + c)) * DSTATE * DINNER + d;
#pragma unroll
  for (int n = 0; n < DSTATE; ++n) {
    PBUF[base + (size_t)n * DINNER] = P[n];
    HBUF[base + (size_t)n * DINNER] = h[n];
  }
}

// ---------------------------------------------------------------------------
// Scan combine: sequential prefix across 32 chunks per (b,n,d).
// ---------------------------------------------------------------------------
__global__ __launch_bounds__(256) void scan_combine(
    const float* __restrict__ PBUF, float* __restrict__ HBUF) {
  const int bx = blockIdx.x;
  const int b = bx >> 7;
  const int n = (bx >> 3) & (DSTATE - 1);
  const int d = ((bx & 7) << 8) + threadIdx.x;
  float h = 0.f;
  for (int c = 0; c < NCHUNK; ++c) {
    size_t idx = (((size_t)(b * NCHUNK + c)) * DSTATE + n) * DINNER + d;
    float p = PBUF[idx];
    float hl = HBUF[idx];
    HBUF[idx] = h;
    h = p * h + hl;
  }
}

// ---------------------------------------------------------------------------
// Scan pass 2: rescan from incoming state; y = C.h + u*D, gate silu(res),
// emit bf16 Y.
// ---------------------------------------------------------------------------
__global__ __launch_bounds__(256) void scan_pass2(
    const unsigned short* __restrict__ DELTAB, const unsigned short* __restrict__ UB,
    const float* __restrict__ BC, const float* __restrict__ HBUF,
    const float* __restrict__ A_log, const float* __restrict__ D_param,
    const unsigned short* __restrict__ RESB, unsigned short* __restrict__ YB) {
  const int bx = blockIdx.x;
  const int b = bx >> 8;
  const int c = (bx >> 3) & (NCHUNK - 1);
  const int d = ((bx & 7) << 8) + threadIdx.x;
  const int l0 = c * LCHUNK;
  __shared__ float sBC[LCHUNK * 32];
#pragma unroll
  for (int i = 0; i < 4; ++i) {
    int e = threadIdx.x + i * 256;
    sBC[e] = BC[((size_t)(b * LSEQ + l0 + (e >> 5))) * 32 + (e & 31)];
  }
  float Avv[DSTATE];
#pragma unroll
  for (int n = 0; n < DSTATE; ++n) Avv[n] = -__expf(A_log[d * DSTATE + n]);
  const float Dp = D_param[d];
  float h[DSTATE];
  size_t base = ((size_t)(b * NCHUNK + c)) * DSTATE * DINNER + d;
#pragma unroll
  for (int n = 0; n < DSTATE; ++n) h[n] = HBUF[base + (size_t)n * DINNER];
  __syncthreads();
  for (int lc = 0; lc < LCHUNK; ++lc) {
    size_t off = ((size_t)(b * LSEQ + l0 + lc)) * DINNER + d;
    float delta = bf2f(DELTAB[off]);
    float uu = bf2f(UB[off]);
    float du = delta * uu;
    float y = 0.f;
#pragma unroll
    for (int n = 0; n < DSTATE; ++n) {
      float dA = __expf(delta * Avv[n]);
      h[n] = dA * h[n] + du * sBC[lc * 32 + n];
      y += h[n] * sBC[lc * 32 + 16 + n];
    }
    y += uu * Dp;
    float r = bf2f(RESB[off]);
    YB[off] = f2bf(y * (r / (1.f + __expf(-r))));
  }
}

// ---------------------------------------------------------------------------
extern "C" void kernel_launch(void* const* d_in, const int* in_sizes, int n_in,
                              void* d_out, int out_size, void* d_ws, size_t ws_size,
                              hipStream_t stream) {
  const float* x       = (const float*)d_in[0];
  const float* w_in    = (const float*)d_in[1];
  const float* conv_w  = (const float*)d_in[2];
  const float* conv_b  = (const float*)d_in[3];
  const float* xproj_w = (const float*)d_in[4];
  const float* dt_w    = (const float*)d_in[5];
  const float* dt_b    = (const float*)d_in[6];
  const float* A_log   = (const float*)d_in[7];
  const float* D_par   = (const float*)d_in[8];
  const float* out_w   = (const float*)d_in[9];
  float* out = (float*)d_out;

  char* ws = (char*)d_ws;
  const size_t MB = 1024 * 1024;
  // bf16 activation buffers (R1-proven layout)
  unsigned short* UPREB  = (unsigned short*)(ws + 0 * MB);   // 8 MB (dead after conv_xproj)
  unsigned short* RESB   = (unsigned short*)(ws + 8 * MB);   // 8 MB (dead after scan)
  unsigned short* UB     = (unsigned short*)(ws + 16 * MB);  // 8 MB
  unsigned short* DELTAB = (unsigned short*)(ws + 24 * MB);  // 8 MB
  unsigned short* YB     = (unsigned short*)(ws + 32 * MB);  // 8 MB
  unsigned short* XB     = (unsigned short*)(ws + 40 * MB);  // 4 MB (dead after in_proj)
  unsigned short* WINB   = (unsigned short*)(ws + 44 * MB);  // 8 MB (dead after in_proj)
  unsigned short* DTWB   = (unsigned short*)(ws + 52 * MB);  // 8 MB (dead after dt_proj)
  unsigned short* OWB    = (unsigned short*)(ws + 60 * MB);  // 4 MB (live to end)
  // overlays (first written strictly after underlying buffer dies)
  float* PBUF  = (float*)(ws + 0 * MB);                 // 8 MB over UPREB (w: pass1)
  float* HBUF  = (float*)(ws + 40 * MB);                // 8 MB over XB+WINB[0:4] (w: pass1)
  float* BCb   = (float*)(ws + 48 * MB);                // 256 KB over WINB[4:] (w: pass1)
  float* XPART = (float*)(ws + 48 * MB + 512 * 1024);   // 2 MB over WINB[4:] (w: conv_xproj)
  float* OUT2  = (float*)(ws + 40 * MB);                // 16 MB over HBUF+BCb+DTWB[0:4]
                                                        //   (w: out_proj, AFTER pass2)
  float* DT4   = (float*)(ws + 64 * MB);                // 64 MB, 4 fp32 slabs
  // footprint: 128 MB (ws_size assumed >= 128 MB)

  // input conversions
  cvt_all<<<dim3(12288), dim3(256), 0, stream>>>(
      x, w_in, dt_w, out_w, XB, WINB, DTWB, OWB);
  // in_proj: XB(2048x1024) x WINB(4096x1024)^T -> UPREB | RESB bf16
  // R1-proven config: 512 blocks = 2/CU
  mfma_gemm_nt<128><<<dim3(2 * DINNER / 128, NROWS / 128, 1), dim3(512), 0, stream>>>(
      XB, DMODEL, WINB, DMODEL, UPREB, DINNER, RESB, DINNER, DINNER,
      nullptr, DMODEL, 1);
  // fused conv+silu+x_proj partial -> UB, XPART (16-row tiles, 1024 blocks)
  conv_xproj<<<dim3(8, NROWS / 16), dim3(256), 0, stream>>>(
      UPREB, conv_w, conv_b, xproj_w, UB, XPART);
  // dt_proj: UB x DTWB^T, split-K=4 -> DT4 fp32 slabs (1024 blocks = 4/CU)
  mfma_gemm_nt<128><<<dim3(DINNER / 128, NROWS / 128, 4), dim3(512), 0, stream>>>(
      UB, DINNER, DTWB, DINNER, DT4, DINNER, nullptr, 0, NROWS * DINNER,
      nullptr, DINNER / 4, 3);
  // dt partial reduce + bias + softplus -> DELTAB bf16
  dt_reduce<<<dim3(4096), dim3(256), 0, stream>>>(DT4, dt_b, DELTAB);
  // chunked selective scan (pass1 folds the x_proj reduce)
  scan_pass1<<<dim3(BATCH * NCHUNK * (DINNER / 256)), dim3(256), 0, stream>>>(
      DELTAB, UB, XPART, BCb, A_log, PBUF, HBUF);
  scan_combine<<<dim3(BATCH * DSTATE * (DINNER / 256)), dim3(256), 0, stream>>>(PBUF, HBUF);
  scan_pass2<<<dim3(BATCH * NCHUNK * (DINNER / 256)), dim3(256), 0, stream>>>(
      DELTAB, UB, BCb, HBUF, A_log, D_par, RESB, YB);
  // out_proj: YB(2048x2048) x OWB(1024x2048)^T, split-K=2 -> OUT2 fp32 slabs
  // (512 blocks = 2/CU)
  mfma_gemm_nt<64><<<dim3(DMODEL / 64, NROWS / 128, 2), dim3(512), 0, stream>>>(
      YB, DINNER, OWB, DINNER, OUT2, DMODEL, nullptr, 0, NROWS * DMODEL,
      nullptr, DINNER / 2, 3);
  // out partial reduce -> d_out fp32
  out_reduce<<<dim3(2048), dim3(256), 0, stream>>>(OUT2, out);
}

// Round 6
// 259.600 us; speedup vs baseline: 1.4774x; 1.1732x over previous
//
#include <hip/hip_runtime.h>
#include <math.h>

// Problem constants
#define BATCH   2
#define LSEQ    1024
#define DMODEL  1024
#define DSTATE  16
#define DCONV   4
#define DINNER  2048
#define NROWS   (BATCH * LSEQ)   // 2048

#define LCHUNK  32
#define NCHUNK  32

typedef short  bf16x8 __attribute__((ext_vector_type(8)));
typedef float  f32x4  __attribute__((ext_vector_type(4)));

__device__ __forceinline__ unsigned short f2bf(float f) {
  unsigned int u = __builtin_bit_cast(unsigned int, f);
  u = (u + 0x7fffu + ((u >> 16) & 1u)) >> 16;   // RNE
  return (unsigned short)u;
}
__device__ __forceinline__ float bf2f(unsigned short h) {
  return __builtin_bit_cast(float, (unsigned int)h << 16);
}
__device__ __forceinline__ float softplus_f(float v) {
  return (v > 20.f) ? v : __logf(1.f + __expf(v));
}

// ---------------------------------------------------------------------------
// Fused input conversion (R13-proven). 4 regions.
// ---------------------------------------------------------------------------
__device__ __forceinline__ void cvt_ew_body(const float* __restrict__ s,
                                            unsigned short* __restrict__ d,
                                            int blk, int tid) {
  int i = blk * 256 + tid;
  float4 v = ((const float4*)s)[i];
  ushort4 o;
  o.x = f2bf(v.x); o.y = f2bf(v.y); o.z = f2bf(v.z); o.w = f2bf(v.w);
  ((ushort4*)d)[i] = o;
}

__device__ __forceinline__ void cvt_tr_body(const float* __restrict__ s,
                                            unsigned short* __restrict__ d,
                                            int R, int C, int c0, int r0,
                                            int tid, float (*T)[33]) {
#pragma unroll
  for (int i = 0; i < 4; ++i) {
    int e = tid + i * 256;
    int r = e >> 5, c = e & 31;
    T[r][c] = s[(size_t)(r0 + r) * C + c0 + c];
  }
  __syncthreads();
#pragma unroll
  for (int i = 0; i < 4; ++i) {
    int e = tid + i * 256;
    int c = e >> 5, r = e & 31;
    d[(size_t)(c0 + c) * R + r0 + r] = f2bf(T[r][c]);
  }
}

__global__ __launch_bounds__(256) void cvt_all(
    const float* __restrict__ x, const float* __restrict__ w_in,
    const float* __restrict__ dt_w, const float* __restrict__ out_w,
    unsigned short* __restrict__ XB, unsigned short* __restrict__ WINB,
    unsigned short* __restrict__ DTWB, unsigned short* __restrict__ OWB) {
  __shared__ float T[32][33];
  const int bid = blockIdx.x;
  const int tid = threadIdx.x;
  if (bid < 2048) {
    cvt_ew_body(x, XB, bid, tid);
  } else if (bid < 6144) {
    int t = bid - 2048;
    cvt_tr_body(w_in, WINB, 1024, 4096, (t & 127) * 32, (t >> 7) * 32, tid, T);
  } else if (bid < 10240) {
    cvt_ew_body(dt_w, DTWB, bid - 6144, tid);
  } else {
    int t = bid - 10240;
    cvt_tr_body(out_w, OWB, 2048, 1024, (t & 31) * 32, (t >> 5) * 32, tid, T);
  }
}

// ---------------------------------------------------------------------------
// bf16 MFMA GEMM (NT), BM=128 x BN (template), BK=64, 512 threads, 8 waves
// 2(row)x4(col), LDS 16 + BN/8 KB single-buffer, 2-phase loop.
// R6: COALESCED + SWIZZLED STAGING. R0-R5 fit: per-CU global_load_lds rate
// pinned at 18-25 GB/s across ALL schedule/depth/occupancy variants ->
// transaction-rate-bound. Old staging mapped consecutive lanes to
// consecutive ROWS (stride lda*2B = 2-4 KB): each wave instr = 64-cache-line
// gather. New: LDS is row-major [row][64 K-elems]; slot s <-> global
// (row = s>>3, kc = (s&7) ^ (row&7)). A wave covers 8 rows x 128 contiguous
// bytes = 16 lines/instr (4x fewer transactions). The kc XOR (involution,
// source-side pre-swizzle per m173; LDS dest stays linear) keeps the
// ds_read_b128 fragment-read bank profile identical to the old proven
// layout (8 lanes/16B-column, measured conflict-free). Readers use
// slot = row*8 + (kc ^ (row&7)).
// R5: split-K with plain fp32 slab stores (atomics cost ~7 µs/M — R2).
// Epilogue modes: 1 = bf16 col<N1 -> C1 else C2   [in_proj u|res]
//                 3 = fp32 store to slab blockIdx.z (slab elems in N1)
// NOTE (R8/R11): NO inter-block coordination inside kernels.
// ---------------------------------------------------------------------------
template <int BN>
__global__ __launch_bounds__(512) void mfma_gemm_nt(
    const unsigned short* __restrict__ A, int lda,
    const unsigned short* __restrict__ Bt, int ldb,
    void* __restrict__ C1v, int ld1,
    void* __restrict__ C2v, int ld2, int N1,
    const float* __restrict__ bias,
    int KS, int mode) {
  constexpr int NT = BN / 64;                 // col MFMA tiles per wave
  __shared__ unsigned short As[8 * 128 * 8];  // 16 KB [row][kc_swz][8]
  __shared__ unsigned short Bs[8 * BN * 8];   // BN/8 KB [col][kc_swz][8]
  const int tid  = threadIdx.x;
  const int wave = tid >> 6;        // 0..7
  const int lane = tid & 63;
  const int linear = blockIdx.y * gridDim.x + blockIdx.x;
  const int xcd = linear & 7;
  const int pos = linear >> 3;
  const int row0 = (xcd * 2 + (pos & 1)) * 128;   // 16 M-panels (M=2048)
  const int col0 = (pos >> 1) * BN;
  const int wm0 = (wave >> 2) * 64;
  const int wn0 = (wave & 3) * (BN / 4);
  const int kb = blockIdx.z * KS;

  f32x4 acc[4][NT];
#pragma unroll
  for (int i = 0; i < 4; ++i)
#pragma unroll
    for (int j = 0; j < NT; ++j) acc[i][j] = (f32x4){0.f, 0.f, 0.f, 0.f};

  const int lkc = lane >> 4, li = lane & 15;
  const int sw = li & 7;            // read-side XOR key (row&7 == li&7)
  for (int k0 = kb; k0 < kb + KS; k0 += 64) {
#pragma unroll
    for (int it = 0; it < 2; ++it) {
      int s = it * 512 + tid;        // 0..1023 A slots (16B each)
      int r = s >> 3;                // row 0..127
      int kc = (s & 7) ^ (r & 7);    // swizzled K-chunk
      __builtin_amdgcn_global_load_lds(
          (const __attribute__((address_space(1))) void*)(A + (size_t)(row0 + r) * lda + k0 + kc * 8),
          (__attribute__((address_space(3))) void*)(&As[s * 8]), 16, 0, 0);
    }
#pragma unroll
    for (int it = 0; it < BN / 64; ++it) {
      int s = it * 512 + tid;        // 0..8*BN-1 B slots
      int r = s >> 3;                // col 0..BN-1
      int kc = (s & 7) ^ (r & 7);
      __builtin_amdgcn_global_load_lds(
          (const __attribute__((address_space(1))) void*)(Bt + (size_t)(col0 + r) * ldb + k0 + kc * 8),
          (__attribute__((address_space(3))) void*)(&Bs[s * 8]), 16, 0, 0);
    }
    __syncthreads();
#pragma unroll
    for (int half = 0; half < 2; ++half) {
      bf16x8 af[4], bfr[NT];
#pragma unroll
      for (int mt = 0; mt < 4; ++mt) {
        int ra = wm0 + mt * 16 + li;
        af[mt] = *(const bf16x8*)&As[(ra * 8 + ((half * 4 + lkc) ^ sw)) * 8];
      }
#pragma unroll
      for (int nt = 0; nt < NT; ++nt) {
        int rb = wn0 + nt * 16 + li;
        bfr[nt] = *(const bf16x8*)&Bs[(rb * 8 + ((half * 4 + lkc) ^ sw)) * 8];
      }
#pragma unroll
      for (int mt = 0; mt < 4; ++mt)
#pragma unroll
        for (int nt = 0; nt < NT; ++nt)
          acc[mt][nt] = __builtin_amdgcn_mfma_f32_16x16x32_bf16(
              af[mt], bfr[nt], acc[mt][nt], 0, 0, 0);
    }
    __syncthreads();
  }
  // C/D layout: col=lane&15, row=(lane>>4)*4+reg (m89-verified)
  const int lq = lane >> 4;
#pragma unroll
  for (int mt = 0; mt < 4; ++mt) {
    int gm0 = row0 + wm0 + mt * 16 + lq * 4;
#pragma unroll
    for (int nt = 0; nt < NT; ++nt) {
      int gn = col0 + wn0 + nt * 16 + li;
      if (mode == 1) {
        if (gn < N1) {
          unsigned short* C1 = (unsigned short*)C1v;
#pragma unroll
          for (int r = 0; r < 4; ++r)
            C1[(size_t)(gm0 + r) * ld1 + gn] = f2bf(acc[mt][nt][r]);
        } else {
          unsigned short* C2 = (unsigned short*)C2v;
#pragma unroll
          for (int r = 0; r < 4; ++r)
            C2[(size_t)(gm0 + r) * ld2 + gn - N1] = f2bf(acc[mt][nt][r]);
        }
      } else {  // mode 3: fp32 plain store into partial slab blockIdx.z
        float* C1 = (float*)C1v + (size_t)blockIdx.z * (size_t)N1;
#pragma unroll
        for (int r = 0; r < 4; ++r)
          C1[(size_t)(gm0 + r) * ld1 + gn] = acc[mt][nt][r];
      }
    }
  }
}

// ---------------------------------------------------------------------------
// dt partial reduce: DELTAB = softplus(sum_z DT4[z] + dt_b[col]) -> bf16.
// ---------------------------------------------------------------------------
__global__ __launch_bounds__(256) void dt_reduce(
    const float* __restrict__ P, const float* __restrict__ dtb,
    unsigned short* __restrict__ D) {
  const size_t SL = (size_t)NROWS * DINNER;       // 4M floats per slab
  size_t i4 = (size_t)blockIdx.x * 256 + threadIdx.x;
  float4 a = ((const float4*)P)[i4];
  float4 b = ((const float4*)(P + SL))[i4];
  float4 c = ((const float4*)(P + 2 * SL))[i4];
  float4 d = ((const float4*)(P + 3 * SL))[i4];
  int col = (int)((i4 * 4) & (DINNER - 1));
  float4 bb = *(const float4*)&dtb[col];
  ushort4 o;
  o.x = f2bf(softplus_f(a.x + b.x + c.x + d.x + bb.x));
  o.y = f2bf(softplus_f(a.y + b.y + c.y + d.y + bb.y));
  o.z = f2bf(softplus_f(a.z + b.z + c.z + d.z + bb.z));
  o.w = f2bf(softplus_f(a.w + b.w + c.w + d.w + bb.w));
  ((ushort4*)D)[i4] = o;
}

// ---------------------------------------------------------------------------
// out partial reduce: out = OUT2[0] + OUT2[1] (fp32).
// ---------------------------------------------------------------------------
__global__ __launch_bounds__(256) void out_reduce(
    const float* __restrict__ P, float* __restrict__ out) {
  const size_t SL = (size_t)NROWS * DMODEL;       // 2M floats per slab
  size_t i4 = (size_t)blockIdx.x * 256 + threadIdx.x;
  float4 a = ((const float4*)P)[i4];
  float4 b = ((const float4*)(P + SL))[i4];
  ((float4*)out)[i4] = make_float4(a.x + b.x, a.y + b.y, a.z + b.z, a.w + b.w);
}

// ---------------------------------------------------------------------------
// Fused depthwise conv(4)+SiLU + x_proj partial (R13-proven, unchanged).
// ---------------------------------------------------------------------------
__global__ __launch_bounds__(256) void conv_xproj(
    const unsigned short* __restrict__ UPREB, const float* __restrict__ cw,
    const float* __restrict__ cb, const float* __restrict__ W,
    unsigned short* __restrict__ UB, float* __restrict__ XPART) {
  const int ks = blockIdx.x;        // 0..7
  const int rt = blockIdx.y;        // 0..127
  const int row0 = rt * 16;
  const int kbase = ks * 256;
  __shared__ unsigned short sU[16][256];  // 8 KB
  __shared__ float Bv[256 * 32];          // 32 KB
  const int tid = threadIdx.x;

  for (int i = tid; i < 256 * 32; i += 256)
    Bv[i] = W[(size_t)(kbase + (i >> 5)) * 32 + (i & 31)];

  {
    const int d = kbase + tid;
    const float w0 = cw[d * DCONV + 0], w1 = cw[d * DCONV + 1];
    const float w2 = cw[d * DCONV + 2], w3 = cw[d * DCONV + 3];
    const float bias = cb[d];
    float x0, x1, x2;
    if ((row0 & (LSEQ - 1)) == 0) {
      x0 = x1 = x2 = 0.f;
    } else {
      x0 = bf2f(UPREB[(size_t)(row0 - 3) * DINNER + d]);
      x1 = bf2f(UPREB[(size_t)(row0 - 2) * DINNER + d]);
      x2 = bf2f(UPREB[(size_t)(row0 - 1) * DINNER + d]);
    }
    for (int r = 0; r < 16; ++r) {
      float x3 = bf2f(UPREB[(size_t)(row0 + r) * DINNER + d]);
      float a = bias + x0 * w0 + x1 * w1 + x2 * w2 + x3 * w3;
      float u = a / (1.f + __expf(-a));
      unsigned short ub = f2bf(u);
      sU[r][tid] = ub;
      UB[(size_t)(row0 + r) * DINNER + d] = ub;
      x0 = x1; x1 = x2; x2 = x3;
    }
  }
  __syncthreads();

  // x_proj partial: C[16][32] = sU[16][256] @ W[256][32]; 8 groups x 2 rows
  const int col = tid & 31, rg = tid >> 5;
  float acc[2] = {};
  for (int k = 0; k < 256; k += 2) {
    float b0 = Bv[k * 32 + col], b1 = Bv[(k + 1) * 32 + col];
#pragma unroll
    for (int rr = 0; rr < 2; ++rr) {
      ushort2 uv = *(const ushort2*)&sU[rg * 2 + rr][k];
      acc[rr] += bf2f(uv.x) * b0 + bf2f(uv.y) * b1;
    }
  }
#pragma unroll
  for (int rr = 0; rr < 2; ++rr)
    XPART[(size_t)ks * NROWS * 32 + (size_t)(row0 + rg * 2 + rr) * 32 + col] = acc[rr];
}

// ---------------------------------------------------------------------------
// Scan pass 1 + inline x_proj reduce (R13-proven).
// ---------------------------------------------------------------------------
__global__ __launch_bounds__(256) void scan_pass1(
    const unsigned short* __restrict__ DELTAB, const unsigned short* __restrict__ UB,
    const float* __restrict__ XPART, float* __restrict__ BCb,
    const float* __restrict__ A_log,
    float* __restrict__ PBUF, float* __restrict__ HBUF) {
  const int bx = blockIdx.x;
  const int b = bx >> 8;
  const int c = (bx >> 3) & (NCHUNK - 1);
  const int d = ((bx & 7) << 8) + threadIdx.x;
  const int l0 = c * LCHUNK;
  __shared__ float sB[LCHUNK * DSTATE];
#pragma unroll
  for (int i = 0; i < 2; ++i) {
    int e = threadIdx.x + i * 256;       // 32 rows x 16 cols
    int row = e >> 4, col = e & 15;
    size_t base = (size_t)(b * LSEQ + l0 + row) * 32 + col;
    float s = 0.f;
#pragma unroll
    for (int ks = 0; ks < 8; ++ks) s += XPART[(size_t)ks * NROWS * 32 + base];
    sB[e] = s;
  }
  if ((bx & 7) == 0) {
#pragma unroll
    for (int i = 0; i < 4; ++i) {
      int e = threadIdx.x + i * 256;     // 32 rows x 32 cols
      int row = e >> 5, col = e & 31;
      size_t base = (size_t)(b * LSEQ + l0 + row) * 32 + col;
      float s = 0.f;
#pragma unroll
      for (int ks = 0; ks < 8; ++ks) s += XPART[(size_t)ks * NROWS * 32 + base];
      BCb[base] = s;
    }
  }
  float Avv[DSTATE];
#pragma unroll
  for (int n = 0; n < DSTATE; ++n) Avv[n] = -__expf(A_log[d * DSTATE + n]);
  float h[DSTATE], P[DSTATE];
#pragma unroll
  for (int n = 0; n < DSTATE; ++n) { h[n] = 0.f; P[n] = 1.f; }
  __syncthreads();
  for (int lc = 0; lc < LCHUNK; ++lc) {
    size_t off = ((size_t)(b * LSEQ + l0 + lc)) * DINNER + d;
    float delta = bf2f(DELTAB[off]);
    float du = delta * bf2f(UB[off]);
#pragma unroll
    for (int n = 0; n < DSTATE; ++n) {
      float dA = __expf(delta * Avv[n]);
      P[n] *= dA;
      h[n] = dA * h[n] + du * sB[lc * DSTATE + n];
    }
  }
  size_t base = ((size_t)(b * NCHUNK + c)) * DSTATE * DINNER + d;
#pragma unroll
  for (int n = 0; n < DSTATE; ++n) {
    PBUF[base + (size_t)n * DINNER] = P[n];
    HBUF[base + (size_t)n * DINNER] = h[n];
  }
}

// ---------------------------------------------------------------------------
// Scan combine: sequential prefix across 32 chunks per (b,n,d).
// ---------------------------------------------------------------------------
__global__ __launch_bounds__(256) void scan_combine(
    const float* __restrict__ PBUF, float* __restrict__ HBUF) {
  const int bx = blockIdx.x;
  const int b = bx >> 7;
  const int n = (bx >> 3) & (DSTATE - 1);
  const int d = ((bx & 7) << 8) + threadIdx.x;
  float h = 0.f;
  for (int c = 0; c < NCHUNK; ++c) {
    size_t idx = (((size_t)(b * NCHUNK + c)) * DSTATE + n) * DINNER + d;
    float p = PBUF[idx];
    float hl = HBUF[idx];
    HBUF[idx] = h;
    h = p * h + hl;
  }
}

// ---------------------------------------------------------------------------
// Scan pass 2: rescan from incoming state; y = C.h + u*D, gate silu(res),
// emit bf16 Y.
// ---------------------------------------------------------------------------
__global__ __launch_bounds__(256) void scan_pass2(
    const unsigned short* __restrict__ DELTAB, const unsigned short* __restrict__ UB,
    const float* __restrict__ BC, const float* __restrict__ HBUF,
    const float* __restrict__ A_log, const float* __restrict__ D_param,
    const unsigned short* __restrict__ RESB, unsigned short* __restrict__ YB) {
  const int bx = blockIdx.x;
  const int b = bx >> 8;
  const int c = (bx >> 3) & (NCHUNK - 1);
  const int d = ((bx & 7) << 8) + threadIdx.x;
  const int l0 = c * LCHUNK;
  __shared__ float sBC[LCHUNK * 32];
#pragma unroll
  for (int i = 0; i < 4; ++i) {
    int e = threadIdx.x + i * 256;
    sBC[e] = BC[((size_t)(b * LSEQ + l0 + (e >> 5))) * 32 + (e & 31)];
  }
  float Avv[DSTATE];
#pragma unroll
  for (int n = 0; n < DSTATE; ++n) Avv[n] = -__expf(A_log[d * DSTATE + n]);
  const float Dp = D_param[d];
  float h[DSTATE];
  size_t base = ((size_t)(b * NCHUNK + c)) * DSTATE * DINNER + d;
#pragma unroll
  for (int n = 0; n < DSTATE; ++n) h[n] = HBUF[base + (size_t)n * DINNER];
  __syncthreads();
  for (int lc = 0; lc < LCHUNK; ++lc) {
    size_t off = ((size_t)(b * LSEQ + l0 + lc)) * DINNER + d;
    float delta = bf2f(DELTAB[off]);
    float uu = bf2f(UB[off]);
    float du = delta * uu;
    float y = 0.f;
#pragma unroll
    for (int n = 0; n < DSTATE; ++n) {
      float dA = __expf(delta * Avv[n]);
      h[n] = dA * h[n] + du * sBC[lc * 32 + n];
      y += h[n] * sBC[lc * 32 + 16 + n];
    }
    y += uu * Dp;
    float r = bf2f(RESB[off]);
    YB[off] = f2bf(y * (r / (1.f + __expf(-r))));
  }
}

// ---------------------------------------------------------------------------
extern "C" void kernel_launch(void* const* d_in, const int* in_sizes, int n_in,
                              void* d_out, int out_size, void* d_ws, size_t ws_size,
                              hipStream_t stream) {
  const float* x       = (const float*)d_in[0];
  const float* w_in    = (const float*)d_in[1];
  const float* conv_w  = (const float*)d_in[2];
  const float* conv_b  = (const float*)d_in[3];
  const float* xproj_w = (const float*)d_in[4];
  const float* dt_w    = (const float*)d_in[5];
  const float* dt_b    = (const float*)d_in[6];
  const float* A_log   = (const float*)d_in[7];
  const float* D_par   = (const float*)d_in[8];
  const float* out_w   = (const float*)d_in[9];
  float* out = (float*)d_out;

  char* ws = (char*)d_ws;
  const size_t MB = 1024 * 1024;
  // bf16 activation buffers (R1-proven layout)
  unsigned short* UPREB  = (unsigned short*)(ws + 0 * MB);   // 8 MB (dead after conv_xproj)
  unsigned short* RESB   = (unsigned short*)(ws + 8 * MB);   // 8 MB (dead after scan)
  unsigned short* UB     = (unsigned short*)(ws + 16 * MB);  // 8 MB
  unsigned short* DELTAB = (unsigned short*)(ws + 24 * MB);  // 8 MB
  unsigned short* YB     = (unsigned short*)(ws + 32 * MB);  // 8 MB
  unsigned short* XB     = (unsigned short*)(ws + 40 * MB);  // 4 MB (dead after in_proj)
  unsigned short* WINB   = (unsigned short*)(ws + 44 * MB);  // 8 MB (dead after in_proj)
  unsigned short* DTWB   = (unsigned short*)(ws + 52 * MB);  // 8 MB (dead after dt_proj)
  unsigned short* OWB    = (unsigned short*)(ws + 60 * MB);  // 4 MB (live to end)
  // overlays (first written strictly after underlying buffer dies)
  float* PBUF  = (float*)(ws + 0 * MB);                 // 8 MB over UPREB (w: pass1)
  float* HBUF  = (float*)(ws + 40 * MB);                // 8 MB over XB+WINB[0:4] (w: pass1)
  float* BCb   = (float*)(ws + 48 * MB);                // 256 KB over WINB[4:] (w: pass1)
  float* XPART = (float*)(ws + 48 * MB + 512 * 1024);   // 2 MB over WINB[4:] (w: conv_xproj)
  float* OUT2  = (float*)(ws + 40 * MB);                // 16 MB over HBUF+BCb+DTWB[0:4]
                                                        //   (w: out_proj, AFTER pass2)
  float* DT4   = (float*)(ws + 64 * MB);                // 64 MB, 4 fp32 slabs
  // footprint: 128 MB (ws_size assumed >= 128 MB)

  // input conversions
  cvt_all<<<dim3(12288), dim3(256), 0, stream>>>(
      x, w_in, dt_w, out_w, XB, WINB, DTWB, OWB);
  // in_proj: XB(2048x1024) x WINB(4096x1024)^T -> UPREB | RESB bf16
  // 512 blocks = 2/CU
  mfma_gemm_nt<128><<<dim3(2 * DINNER / 128, NROWS / 128, 1), dim3(512), 0, stream>>>(
      XB, DMODEL, WINB, DMODEL, UPREB, DINNER, RESB, DINNER, DINNER,
      nullptr, DMODEL, 1);
  // fused conv+silu+x_proj partial -> UB, XPART (16-row tiles, 1024 blocks)
  conv_xproj<<<dim3(8, NROWS / 16), dim3(256), 0, stream>>>(
      UPREB, conv_w, conv_b, xproj_w, UB, XPART);
  // dt_proj: UB x DTWB^T, split-K=4 -> DT4 fp32 slabs (1024 blocks = 4/CU)
  mfma_gemm_nt<128><<<dim3(DINNER / 128, NROWS / 128, 4), dim3(512), 0, stream>>>(
      UB, DINNER, DTWB, DINNER, DT4, DINNER, nullptr, 0, NROWS * DINNER,
      nullptr, DINNER / 4, 3);
  // dt partial reduce + bias + softplus -> DELTAB bf16
  dt_reduce<<<dim3(4096), dim3(256), 0, stream>>>(DT4, dt_b, DELTAB);
  // chunked selective scan (pass1 folds the x_proj reduce)
  scan_pass1<<<dim3(BATCH * NCHUNK * (DINNER / 256)), dim3(256), 0, stream>>>(
      DELTAB, UB, XPART, BCb, A_log, PBUF, HBUF);
  scan_combine<<<dim3(BATCH * DSTATE * (DINNER / 256)), dim3(256), 0, stream>>>(PBUF, HBUF);
  scan_pass2<<<dim3(BATCH * NCHUNK * (DINNER / 256)), dim3(256), 0, stream>>>(
      DELTAB, UB, BCb, HBUF, A_log, D_par, RESB, YB);
  // out_proj: YB(2048x2048) x OWB(1024x2048)^T, split-K=2 -> OUT2 fp32 slabs
  // (512 blocks = 2/CU)
  mfma_gemm_nt<64><<<dim3(DMODEL / 64, NROWS / 128, 2), dim3(512), 0, stream>>>(
      YB, DINNER, OWB, DINNER, OUT2, DMODEL, nullptr, 0, NROWS * DMODEL,
      nullptr, DINNER / 2, 3);
  // out partial reduce -> d_out fp32
  out_reduce<<<dim3(2048), dim3(256), 0, stream>>>(OUT2, out);
}